// Round 1
// 1765.447 us; speedup vs baseline: 1.2735x; 1.2735x over previous
//
#include <hip/hip_runtime.h>
#include <cstdint>
#include <cstddef>

#define DEVI __device__ __forceinline__

typedef __attribute__((ext_vector_type(8))) short short8;   // 8 bf16 = 4 VGPRs
typedef __attribute__((ext_vector_type(4))) float float4v;  // MFMA acc

DEVI float silu_f(float x) { return x / (1.f + __expf(-x)); }

DEVI unsigned short f2bf(float f) {
    union { float f; unsigned u; } x{f};
    unsigned r = x.u + 0x7FFF + ((x.u >> 16) & 1);  // RNE
    return (unsigned short)(r >> 16);
}
DEVI unsigned pack2(float a, float b) {
    return (unsigned)f2bf(a) | ((unsigned)f2bf(b) << 16);
}

// ---------------------------------------------------------------------------
// Weight pre-convert: src[K][N] fp32 -> dst[N][K] bf16 (transposed), 10 mats.
// ---------------------------------------------------------------------------
struct WDesc { const float* src; unsigned short* dst; int K; int N; };
struct WPack { WDesc d[10]; };

__global__ __launch_bounds__(256) void cvt_all_k(WPack p) {
    const WDesc w = p.d[blockIdx.y];
    const int total = w.K * w.N;
    const int ln = (w.N == 256) ? 8 : 7;  // N is 128 or 256
    const int nm = w.N - 1;
    for (int idx = blockIdx.x * 256 + threadIdx.x; idx < total; idx += gridDim.x * 256) {
        int k = idx >> ln, n = idx & nm;
        w.dst[(size_t)n * w.K + k] = f2bf(w.src[idx]);
    }
}

// ---------------------------------------------------------------------------
// bf16 MFMA GEMM: out[M,128] = epi( stage(X)[M,K] @ W[K,128] )
// WT is pre-transposed bf16: WT[n][k], ldwt = K.
// STAGE: 0 raw, 1 LayerNorm over K=128 row
// Block 256 thr = 4 waves; tile M=128 x N=128, BK=64 (2 MFMA k-steps).
// ---------------------------------------------------------------------------
template <int STAGE, bool SILU, bool BIAS, bool RESID>
__global__ __launch_bounds__(256, 2) void mgemm_k(
    const float* __restrict__ X, int M, int ldx, int K,
    const short* __restrict__ WT,
    const float* __restrict__ gamma, const float* __restrict__ beta,
    const float* __restrict__ bias,
    const float* __restrict__ resid, int ldr,
    float* __restrict__ out, int ldo)
{
    __shared__ short Als[128 * 72];
    __shared__ short Bls[128 * 72];
    __shared__ float redS[256];
    __shared__ float redQ[256];

    const int tid  = threadIdx.x;
    const int l    = tid & 63;
    const int w    = tid >> 6;
    const int lanem = l & 15;
    const int laneq = l >> 4;         // quad 0..3
    const int rbase = blockIdx.x * 128;

    // staging role: row sm (0..127), k-half h (0..1)
    const int sm = tid >> 1;
    const int h  = tid & 1;
    const int grow = rbase + sm;
    const bool rowok = grow < M;

    float4v acc[2][8];
#pragma unroll
    for (int mt = 0; mt < 2; mt++)
#pragma unroll
        for (int nt = 0; nt < 8; nt++)
            acc[mt][nt] = (float4v){0.f, 0.f, 0.f, 0.f};

    float mu = 0.f, rstd = 0.f;
    if constexpr (STAGE == 1) {
        // full-row stats pre-pass (K==128 for all STAGE1 uses)
        float s = 0.f, q = 0.f;
        const float* xr = X + (size_t)grow * ldx + h * 64;
#pragma unroll
        for (int i = 0; i < 16; i++) {
            float4 v = rowok ? *(const float4*)(xr + i * 4) : make_float4(0.f, 0.f, 0.f, 0.f);
            s += v.x + v.y + v.z + v.w;
            q += v.x * v.x + v.y * v.y + v.z * v.z + v.w * v.w;
        }
        redS[tid] = s; redQ[tid] = q;
        __syncthreads();
        float ts = redS[sm * 2] + redS[sm * 2 + 1];
        float tq = redQ[sm * 2] + redQ[sm * 2 + 1];
        mu = ts * (1.f / 128.f);
        float var = tq * (1.f / 128.f) - mu * mu;
        rstd = rsqrtf(var + 1e-5f);
    }

    for (int k0 = 0; k0 < K; k0 += 64) {
        const int kb = k0 + h * 32;
        // ---- stage A: 32 fp32 -> 32 bf16 into Als[sm][kb..kb+31]
        float4 v[8];
        {
            const float* xr = X + (size_t)grow * ldx + kb;
#pragma unroll
            for (int i = 0; i < 8; i++)
                v[i] = rowok ? *(const float4*)(xr + i * 4) : make_float4(0.f, 0.f, 0.f, 0.f);
        }
        if constexpr (STAGE == 1) {
#pragma unroll
            for (int i = 0; i < 8; i++) {
                int c = kb + i * 4;
                float4 g4 = *(const float4*)(gamma + c);
                float4 b4 = *(const float4*)(beta + c);
                v[i].x = (v[i].x - mu) * rstd * g4.x + b4.x;
                v[i].y = (v[i].y - mu) * rstd * g4.y + b4.y;
                v[i].z = (v[i].z - mu) * rstd * g4.z + b4.z;
                v[i].w = (v[i].w - mu) * rstd * g4.w + b4.w;
            }
        }
        {
            uint4* ad = (uint4*)(Als + sm * 72 + h * 32);
#pragma unroll
            for (int i = 0; i < 4; i++) {
                uint4 o;
                o.x = pack2(v[i * 2].x, v[i * 2].y);
                o.y = pack2(v[i * 2].z, v[i * 2].w);
                o.z = pack2(v[i * 2 + 1].x, v[i * 2 + 1].y);
                o.w = pack2(v[i * 2 + 1].z, v[i * 2 + 1].w);
                ad[i] = o;
            }
        }
        // ---- stage B: WT row sm (=out col), 32 bf16 direct copy
        {
            const uint4* bs = (const uint4*)(WT + (size_t)sm * K + kb);
            uint4* bd = (uint4*)(Bls + sm * 72 + h * 32);
#pragma unroll
            for (int i = 0; i < 4; i++) bd[i] = bs[i];
        }
        __syncthreads();
        // ---- compute: 2 k-steps of 32
#pragma unroll
        for (int s = 0; s < 2; s++) {
            const int ko = s * 32 + laneq * 8;
            short8 bfr[8];
#pragma unroll
            for (int nt = 0; nt < 8; nt++)
                bfr[nt] = *(const short8*)(Bls + (nt * 16 + lanem) * 72 + ko);
#pragma unroll
            for (int mt = 0; mt < 2; mt++) {
                short8 af = *(const short8*)(Als + (w * 32 + mt * 16 + lanem) * 72 + ko);
#pragma unroll
                for (int nt = 0; nt < 8; nt++)
                    acc[mt][nt] = __builtin_amdgcn_mfma_f32_16x16x32_bf16(
                        af, bfr[nt], acc[mt][nt], 0, 0, 0);
            }
        }
        __syncthreads();
    }

    // ---- epilogue: D[row=quad*4+reg][col=lanem] per (mt,nt)
#pragma unroll
    for (int mt = 0; mt < 2; mt++) {
#pragma unroll
        for (int nt = 0; nt < 8; nt++) {
            const int gc = nt * 16 + lanem;
            float bv = 0.f;
            if constexpr (BIAS) bv = bias[gc];
            float4v d = acc[mt][nt];
#pragma unroll
            for (int r = 0; r < 4; r++) {
                int gr = rbase + w * 32 + mt * 16 + laneq * 4 + r;
                if (gr < M) {
                    float o = d[r] + bv;
                    if constexpr (SILU) o = silu_f(o);
                    if constexpr (RESID) o += resid[(size_t)gr * ldr + gc];
                    out[(size_t)gr * ldo + gc] = o;
                }
            }
        }
    }
}

// ---------------------------------------------------------------------------
// CSR-by-dst build: count -> 2-level exclusive scan -> scatter (src,eid)
// ---------------------------------------------------------------------------
__global__ __launch_bounds__(256) void count_k(
    const int* __restrict__ eidx, int* __restrict__ deg, int E)
{
    int e = blockIdx.x * 256 + threadIdx.x;
    if (e < E) atomicAdd(&deg[eidx[(size_t)E + e]], 1);
}

__global__ __launch_bounds__(256) void scan_part_k(
    const int* __restrict__ deg, int* __restrict__ psum, int Nn)
{
    __shared__ int red[256];
    int i = blockIdx.x * 256 + threadIdx.x;
    red[threadIdx.x] = (i < Nn) ? deg[i] : 0;
    __syncthreads();
    for (int s = 128; s > 0; s >>= 1) {
        if (threadIdx.x < s) red[threadIdx.x] += red[threadIdx.x + s];
        __syncthreads();
    }
    if (threadIdx.x == 0) psum[blockIdx.x] = red[0];
}

__global__ __launch_bounds__(1024) void scan_mid_k(int* __restrict__ psum, int P)
{
    __shared__ int sm[1024];
    int t = threadIdx.x;
    int v = (t < P) ? psum[t] : 0;
    sm[t] = v;
    __syncthreads();
    for (int ofs = 1; ofs < 1024; ofs <<= 1) {
        int x = sm[t];
        if (t >= ofs) x += sm[t - ofs];
        __syncthreads();
        sm[t] = x;
        __syncthreads();
    }
    if (t < P) psum[t] = sm[t] - v;  // exclusive
}

// deg_cur aliases: reads deg[i], writes cursor (=exclusive start) back in place.
__global__ __launch_bounds__(256) void scan_fin_k(
    int* __restrict__ deg_cur, const int* __restrict__ psum,
    int* __restrict__ rs, int Nn)
{
    __shared__ int sm[256];
    int i = blockIdx.x * 256 + threadIdx.x;
    int t = threadIdx.x;
    int v = (i < Nn) ? deg_cur[i] : 0;
    sm[t] = v;
    __syncthreads();
    for (int ofs = 1; ofs < 256; ofs <<= 1) {
        int x = sm[t];
        if (t >= ofs) x += sm[t - ofs];
        __syncthreads();
        sm[t] = x;
        __syncthreads();
    }
    if (i < Nn) {
        int excl = sm[t] - v + psum[blockIdx.x];
        rs[i] = excl;
        deg_cur[i] = excl;            // cursor for scatter
        if (i == Nn - 1) rs[Nn] = excl + v;
    }
}

__global__ __launch_bounds__(256) void scatter_k(
    const int* __restrict__ eidx, int* __restrict__ cur,
    int2* __restrict__ csr, int E)
{
    int e = blockIdx.x * 256 + threadIdx.x;
    if (e >= E) return;
    int d = eidx[(size_t)E + e];
    int pos = atomicAdd(&cur[d], 1);
    csr[pos] = make_int2(eidx[e], e);  // (src, eid)
}

// ---------------------------------------------------------------------------
// Edge score: score = clip(K[src]*Q[dst]/4,-5,5)*PE (in-place over PE),
// w[e][h] = exp(clip(head-sum)). 32 lanes/edge. NO atomics, no V read.
// ---------------------------------------------------------------------------
__global__ __launch_bounds__(256) void escore_k(
    const float* __restrict__ Q, const float* __restrict__ Km,
    float* __restrict__ pe_score, const int* __restrict__ eidx,
    float* __restrict__ wE, int E)
{
    int e = blockIdx.x * 8 + (threadIdx.x >> 5);
    if (e >= E) return;
    int lane = threadIdx.x & 31;
    int s = eidx[e];
    int d = eidx[(size_t)E + e];
    size_t co = (size_t)lane * 4;
    float4 qv = *(const float4*)(Q + (size_t)d * 128 + co);
    float4 kv = *(const float4*)(Km + (size_t)s * 128 + co);
    float4 pe = *(const float4*)(pe_score + (size_t)e * 128 + co);
    const float sc = 0.25f;  // 1/sqrt(16)
    float4 sv;
    sv.x = fminf(fmaxf(kv.x * qv.x * sc, -5.f), 5.f) * pe.x;
    sv.y = fminf(fmaxf(kv.y * qv.y * sc, -5.f), 5.f) * pe.y;
    sv.z = fminf(fmaxf(kv.z * qv.z * sc, -5.f), 5.f) * pe.z;
    sv.w = fminf(fmaxf(kv.w * qv.w * sc, -5.f), 5.f) * pe.w;
    *(float4*)(pe_score + (size_t)e * 128 + co) = sv;
    float hs = sv.x + sv.y + sv.z + sv.w;
    hs += __shfl_xor(hs, 1, 64);
    hs += __shfl_xor(hs, 2, 64);
    float w = __expf(fminf(fmaxf(hs, -5.f), 5.f));
    if ((lane & 3) == 0) wE[(size_t)e * 8 + (lane >> 2)] = w;
}

// ---------------------------------------------------------------------------
// Node aggregation: per dst node, sum w*V[src] and z over its CSR edge list,
// write wV/(z+1e-6). 32 lanes/node, register accumulation, no atomics.
// ---------------------------------------------------------------------------
__global__ __launch_bounds__(256) void agg_k(
    const float* __restrict__ V, const float* __restrict__ wE,
    const int2* __restrict__ csr, const int* __restrict__ rs,
    float* __restrict__ out, int Nn)
{
    int n = blockIdx.x * 8 + (threadIdx.x >> 5);
    if (n >= Nn) return;
    int lane = threadIdx.x & 31;
    int h = lane >> 2;
    int b = rs[n], eend = rs[n + 1];
    float ax = 0.f, ay = 0.f, az = 0.f, aw = 0.f, zs = 0.f;
    for (int i = b; i < eend; i++) {
        int2 pr = csr[i];
        float w = wE[(size_t)pr.y * 8 + h];
        float4 vv = *(const float4*)(V + (size_t)pr.x * 128 + (size_t)lane * 4);
        ax += w * vv.x; ay += w * vv.y; az += w * vv.z; aw += w * vv.w;
        zs += w;
    }
    float rz = 1.f / (zs + 1e-6f);
    *(float4*)(out + (size_t)n * 128 + (size_t)lane * 4) =
        make_float4(ax * rz, ay * rz, az * rz, aw * rz);
}

// ---------------------------------------------------------------------------
extern "C" void kernel_launch(void* const* d_in, const int* in_sizes, int n_in,
                              void* d_out, int out_size, void* d_ws, size_t ws_size,
                              hipStream_t stream)
{
    const float* node  = (const float*)d_in[0];
    const float* edgef = (const float*)d_in[1];
    const int*   eidx  = (const int*)d_in[2];
    const float* Wq = (const float*)d_in[3];
    const float* Wk = (const float*)d_in[4];
    const float* Wv = (const float*)d_in[5];
    const float* We = (const float*)d_in[6];
    const float* Wo_n = (const float*)d_in[7];
    const float* bo_n = (const float*)d_in[8];
    const float* Wo_e = (const float*)d_in[9];
    const float* bo_e = (const float*)d_in[10];
    const float* W1n = (const float*)d_in[11];
    const float* W2n = (const float*)d_in[12];
    const float* W1e = (const float*)d_in[13];
    const float* W2e = (const float*)d_in[14];
    const float* g1n = (const float*)d_in[15];
    const float* b1n = (const float*)d_in[16];
    const float* g1e = (const float*)d_in[17];
    const float* b1e = (const float*)d_in[18];
    const float* g2n = (const float*)d_in[19];
    const float* b2n = (const float*)d_in[20];
    const float* g2e = (const float*)d_in[21];
    const float* b2e = (const float*)d_in[22];

    const int N = in_sizes[0] / 128;
    const int E = in_sizes[1] / 128;
    float* outn = (float*)d_out;                    // node region (doubles as h2)
    float* oute = (float*)d_out + (size_t)N * 128;  // edge region: PE->score->e2->e_out

    // ---- workspace: bf16 transposed weights first, then fp32/int buffers ----
    unsigned short* wts = (unsigned short*)d_ws;
    unsigned short* WqT  = wts;            // 128x128
    unsigned short* WkT  = wts + 16384;
    unsigned short* WvT  = wts + 32768;
    unsigned short* WeT  = wts + 49152;
    unsigned short* WonT = wts + 65536;
    unsigned short* WoeT = wts + 81920;
    unsigned short* W1nT = wts + 98304;    // 256x128
    unsigned short* W1eT = wts + 131072;   // 256x128
    unsigned short* W2nT = wts + 163840;   // 128x256
    unsigned short* W2eT = wts + 196608;   // 128x256  (end: 229376 shorts)
    float* p = (float*)(wts + 229376);
    float* Qb  = p; p += (size_t)N * 128;
    float* Kb  = p; p += (size_t)N * 128;
    float* Vb  = p; p += (size_t)N * 128;
    float* wVd = p; p += (size_t)N * 128;   // divided aggregation result
    float* wEb = p; p += (size_t)E * 8;     // per-edge per-head weights
    int* rs   = (int*)p;                    // rowstart, N+1
    int* cur  = rs + (N + 1);               // degree / scatter cursor, N
    int* psum = cur + N;                    // partial sums, up to 1024
    int* csr_i = psum + 1024;
    csr_i = (int*)(((uintptr_t)csr_i + 15) & ~(uintptr_t)15);
    int2* csr = (int2*)csr_i;               // E entries (src, eid)
    p = (float*)(csr + E);
    float* tb = p;
    size_t used = (size_t)((char*)p - (char*)d_ws) / 4;
    size_t total = ws_size / sizeof(float);
    size_t avail = (total > used) ? (total - used) : 0;
    long long chunk = (long long)(avail / 256);
    if (chunk > 60032) chunk = 60032;
    if (chunk < 1024)  chunk = 1024;
    chunk &= ~127LL;

    // ---- weight conversion (one launch, 10 matrices) ----
    {
        WPack pk;
        pk.d[0] = {Wq,   WqT,  128, 128}; pk.d[1] = {Wk,   WkT,  128, 128};
        pk.d[2] = {Wv,   WvT,  128, 128}; pk.d[3] = {We,   WeT,  128, 128};
        pk.d[4] = {Wo_n, WonT, 128, 128}; pk.d[5] = {Wo_e, WoeT, 128, 128};
        pk.d[6] = {W1n,  W1nT, 128, 256}; pk.d[7] = {W1e,  W1eT, 128, 256};
        pk.d[8] = {W2n,  W2nT, 256, 128}; pk.d[9] = {W2e,  W2eT, 256, 128};
        cvt_all_k<<<dim3(128, 10), 256, 0, stream>>>(pk);
    }

    dim3 blk(256);
    const int rbN = (N + 127) / 128;
    const int rbE = (E + 127) / 128;
    const int P = (N + 255) / 256;  // scan partials (196 for N=50000, cap 1024)

    // ---- CSR-by-dst build (cheap; no dependence on GEMMs) ----
    hipMemsetAsync(cur, 0, (size_t)N * sizeof(int), stream);
    count_k<<<(E + 255) / 256, blk, 0, stream>>>(eidx, cur, E);
    scan_part_k<<<P, blk, 0, stream>>>(cur, psum, N);
    scan_mid_k<<<1, 1024, 0, stream>>>(psum, P);
    scan_fin_k<<<P, blk, 0, stream>>>(cur, psum, rs, N);
    scatter_k<<<(E + 255) / 256, blk, 0, stream>>>(eidx, cur, csr, E);

    // 1) Q/K/V = LN1(node) @ {Wq,Wk,Wv}
    mgemm_k<1, false, false, false><<<rbN, blk, 0, stream>>>(
        node, N, 128, 128, (const short*)WqT, g1n, b1n, nullptr, nullptr, 0, Qb, 128);
    mgemm_k<1, false, false, false><<<rbN, blk, 0, stream>>>(
        node, N, 128, 128, (const short*)WkT, g1n, b1n, nullptr, nullptr, 0, Kb, 128);
    mgemm_k<1, false, false, false><<<rbN, blk, 0, stream>>>(
        node, N, 128, 128, (const short*)WvT, g1n, b1n, nullptr, nullptr, 0, Vb, 128);

    // 2) PE = LN1(edge) @ We -> oute
    mgemm_k<1, false, false, false><<<rbE, blk, 0, stream>>>(
        edgef, E, 128, 128, (const short*)WeT, g1e, b1e, nullptr, nullptr, 0, oute, 128);

    // 3a) edge scores + per-head weights (in-place over oute, no atomics)
    escore_k<<<(E + 7) / 8, blk, 0, stream>>>(Qb, Kb, oute, eidx, wEb, E);

    // 3b) node aggregation via CSR: wVd = segsum(w*V[src]) / (segsum(w)+1e-6)
    agg_k<<<(N + 7) / 8, blk, 0, stream>>>(Vb, wEb, csr, rs, wVd, N);

    // 4) h2 = node + wVd @ Wo_n + bo_n -> outn
    mgemm_k<0, false, true, true><<<rbN, blk, 0, stream>>>(
        wVd, N, 128, 128, (const short*)WonT, nullptr, nullptr, bo_n, node, 128, outn, 128);

    // 5) e2 = edge + score @ Wo_e + bo_e (in-place on oute)
    mgemm_k<0, false, true, true><<<rbE, blk, 0, stream>>>(
        oute, E, 128, 128, (const short*)WoeT, nullptr, nullptr, bo_e, edgef, 128, oute, 128);

    // 6) node FFN (chunked, in-place on outn)
    for (long long b = 0; b < N; b += chunk) {
        const int Mc = (int)(((long long)N - b < chunk) ? (N - b) : chunk);
        const int rb = (Mc + 127) / 128;
        float* xc = outn + (size_t)b * 128;
        mgemm_k<1, true, false, false><<<rb, blk, 0, stream>>>(
            xc, Mc, 128, 128, (const short*)W1nT, g2n, b2n, nullptr, nullptr, 0, tb, 256);
        mgemm_k<1, true, false, false><<<rb, blk, 0, stream>>>(
            xc, Mc, 128, 128, (const short*)(W1nT + 128 * 128), g2n, b2n, nullptr, nullptr, 0, tb + 128, 256);
        mgemm_k<0, false, false, true><<<rb, blk, 0, stream>>>(
            tb, Mc, 256, 256, (const short*)W2nT, nullptr, nullptr, nullptr, xc, 128, xc, 128);
    }

    // 7) edge FFN (chunked, in-place on oute)
    for (long long b = 0; b < E; b += chunk) {
        const int Mc = (int)(((long long)E - b < chunk) ? (E - b) : chunk);
        const int rb = (Mc + 127) / 128;
        float* xc = oute + (size_t)b * 128;
        mgemm_k<1, true, false, false><<<rb, blk, 0, stream>>>(
            xc, Mc, 128, 128, (const short*)W1eT, g2e, b2e, nullptr, nullptr, 0, tb, 256);
        mgemm_k<1, true, false, false><<<rb, blk, 0, stream>>>(
            xc, Mc, 128, 128, (const short*)(W1eT + 128 * 128), g2e, b2e, nullptr, nullptr, 0, tb + 128, 256);
        mgemm_k<0, false, false, true><<<rb, blk, 0, stream>>>(
            tb, Mc, 256, 256, (const short*)W2eT, nullptr, nullptr, nullptr, xc, 128, xc, 128);
    }
}

// Round 2
// 1102.551 us; speedup vs baseline: 2.0392x; 1.6012x over previous
//
#include <hip/hip_runtime.h>
#include <cstdint>
#include <cstddef>

#define DEVI __device__ __forceinline__

typedef __attribute__((ext_vector_type(8))) short short8;   // 8 bf16 = 4 VGPRs
typedef __attribute__((ext_vector_type(4))) float float4v;  // MFMA acc

DEVI float silu_f(float x) { return x / (1.f + __expf(-x)); }
DEVI float clip5(float x) { return fminf(fmaxf(x, -5.f), 5.f); }

DEVI unsigned short f2bf(float f) {
    union { float f; unsigned u; } x{f};
    unsigned r = x.u + 0x7FFF + ((x.u >> 16) & 1);  // RNE
    return (unsigned short)(r >> 16);
}
DEVI unsigned pack2(float a, float b) {
    return (unsigned)f2bf(a) | ((unsigned)f2bf(b) << 16);
}

// ---------------------------------------------------------------------------
// Weight pre-convert: src[K][N] fp32 -> dst[N][K] bf16 (transposed), 10 mats.
// ---------------------------------------------------------------------------
struct WDesc { const float* src; unsigned short* dst; int K; int N; };
struct WPack { WDesc d[10]; };

__global__ __launch_bounds__(256) void cvt_all_k(WPack p) {
    const WDesc w = p.d[blockIdx.y];
    const int total = w.K * w.N;
    const int ln = (w.N == 256) ? 8 : 7;  // N is 128 or 256
    const int nm = w.N - 1;
    for (int idx = blockIdx.x * 256 + threadIdx.x; idx < total; idx += gridDim.x * 256) {
        int k = idx >> ln, n = idx & nm;
        w.dst[(size_t)n * w.K + k] = f2bf(w.src[idx]);
    }
}

// ---------------------------------------------------------------------------
// Shared MFMA helpers (4-wave block, M-tile 128, N 128, per-wave 32x128).
// Acc layout: row = w*32 + mt*16 + laneq*4 + r, col = nt*16 + lanem.
// ---------------------------------------------------------------------------
template <int LDA>
DEVI void mfma64s(const short* A, const short* B, int w, int lanem, int laneq,
                  float4v acc[2][8]) {
#pragma unroll
    for (int s = 0; s < 2; s++) {
        const int ko = s * 32 + laneq * 8;
        short8 bfr[8];
#pragma unroll
        for (int nt = 0; nt < 8; nt++)
            bfr[nt] = *(const short8*)(B + (nt * 16 + lanem) * 72 + ko);
#pragma unroll
        for (int mt = 0; mt < 2; mt++) {
            short8 af = *(const short8*)(A + (w * 32 + mt * 16 + lanem) * LDA + ko);
#pragma unroll
            for (int nt = 0; nt < 8; nt++)
                acc[mt][nt] = __builtin_amdgcn_mfma_f32_16x16x32_bf16(
                    af, bfr[nt], acc[mt][nt], 0, 0, 0);
        }
    }
}

DEVI void stageB(short* Bls, const short* WT, int ldw, int koff, int sm, int h) {
    const uint4* bs = (const uint4*)(WT + (size_t)sm * ldw + koff + h * 32);
    uint4* bd = (uint4*)(Bls + sm * 72 + h * 32);
#pragma unroll
    for (int i = 0; i < 4; i++) bd[i] = bs[i];
}

// pack acc-fragment cols [ntb*16, ntb*16+64) -> Als (64-wide, stride 72)
DEVI void packA(short* Als, const float4v a[2][8], int ntb, int w, int lanem, int laneq) {
#pragma unroll
    for (int mt = 0; mt < 2; mt++)
#pragma unroll
        for (int r = 0; r < 4; r++) {
            const int row = w * 32 + mt * 16 + laneq * 4 + r;
#pragma unroll
            for (int nt0 = 0; nt0 < 4; nt0++)
                Als[row * 72 + nt0 * 16 + lanem] = (short)f2bf(a[mt][ntb + nt0][r]);
        }
}

// ---------------------------------------------------------------------------
// QKV fused: stage LN1(node) once -> Xls, then 3 GEMMs (Wq,Wk,Wv).
// ---------------------------------------------------------------------------
__global__ __launch_bounds__(256, 2) void qkv_k(
    const float* __restrict__ X, int M,
    const short* __restrict__ W0, const short* __restrict__ W1, const short* __restrict__ W2,
    const float* __restrict__ g, const float* __restrict__ b,
    float* __restrict__ o0, float* __restrict__ o1, float* __restrict__ o2)
{
    __shared__ short Xls[128 * 136];
    __shared__ short Bls[128 * 72];
    __shared__ float redS[256];
    __shared__ float redQ[256];

    const int tid = threadIdx.x, l = tid & 63, w = tid >> 6;
    const int lanem = l & 15, laneq = l >> 4;
    const int rbase = blockIdx.x * 128;
    const int sm = tid >> 1, h = tid & 1;
    const int grow = rbase + sm;
    const bool rowok = grow < M;

    // LN stats pre-pass
    {
        float s = 0.f, q = 0.f;
        const float* xr = X + (size_t)grow * 128 + h * 64;
#pragma unroll
        for (int i = 0; i < 16; i++) {
            float4 v = rowok ? *(const float4*)(xr + i * 4) : make_float4(0.f, 0.f, 0.f, 0.f);
            s += v.x + v.y + v.z + v.w;
            q += v.x * v.x + v.y * v.y + v.z * v.z + v.w * v.w;
        }
        redS[tid] = s; redQ[tid] = q;
        __syncthreads();
        float ts = redS[sm * 2] + redS[sm * 2 + 1];
        float tq = redQ[sm * 2] + redQ[sm * 2 + 1];
        float mu = ts * (1.f / 128.f);
        float var = tq * (1.f / 128.f) - mu * mu;
        float rstd = rsqrtf(var + 1e-5f);
        // stage LN'd X (both k-halves) into Xls
#pragma unroll
        for (int k0 = 0; k0 < 128; k0 += 64) {
            const int kb = k0 + h * 32;
            const float* xr2 = X + (size_t)grow * 128 + kb;
            float4 v[8];
#pragma unroll
            for (int i = 0; i < 8; i++)
                v[i] = rowok ? *(const float4*)(xr2 + i * 4) : make_float4(0.f, 0.f, 0.f, 0.f);
#pragma unroll
            for (int i = 0; i < 8; i++) {
                int c = kb + i * 4;
                float4 g4 = *(const float4*)(g + c);
                float4 b4 = *(const float4*)(b + c);
                v[i].x = (v[i].x - mu) * rstd * g4.x + b4.x;
                v[i].y = (v[i].y - mu) * rstd * g4.y + b4.y;
                v[i].z = (v[i].z - mu) * rstd * g4.z + b4.z;
                v[i].w = (v[i].w - mu) * rstd * g4.w + b4.w;
            }
            uint4* xd = (uint4*)(Xls + sm * 136 + kb);
#pragma unroll
            for (int i = 0; i < 4; i++) {
                uint4 o;
                o.x = pack2(v[i * 2].x, v[i * 2].y);
                o.y = pack2(v[i * 2].z, v[i * 2].w);
                o.z = pack2(v[i * 2 + 1].x, v[i * 2 + 1].y);
                o.w = pack2(v[i * 2 + 1].z, v[i * 2 + 1].w);
                xd[i] = o;
            }
        }
    }
    __syncthreads();

    const short* Ws[3] = {W0, W1, W2};
    float* outs[3] = {o0, o1, o2};
    for (int j = 0; j < 3; j++) {
        float4v acc[2][8];
#pragma unroll
        for (int mt = 0; mt < 2; mt++)
#pragma unroll
            for (int nt = 0; nt < 8; nt++) acc[mt][nt] = (float4v){0.f, 0.f, 0.f, 0.f};
        for (int k0 = 0; k0 < 128; k0 += 64) {
            stageB(Bls, Ws[j], 128, k0, sm, h);
            __syncthreads();
            mfma64s<136>(Xls + k0, Bls, w, lanem, laneq, acc);
            __syncthreads();
        }
        float* oj = outs[j];
#pragma unroll
        for (int mt = 0; mt < 2; mt++)
#pragma unroll
            for (int nt = 0; nt < 8; nt++) {
                const int gc = nt * 16 + lanem;
#pragma unroll
                for (int r = 0; r < 4; r++) {
                    int gr = rbase + w * 32 + mt * 16 + laneq * 4 + r;
                    if (gr < M) oj[(size_t)gr * 128 + gc] = acc[mt][nt][r];
                }
            }
    }
}

// ---------------------------------------------------------------------------
// MEGA kernel.
// EDGE=true : X=edgef. Phases: LN1 -> PE=@We -> score(clip(QK/4)*PE, wE out)
//             -> e2 = edgef + score@Wo + bo -> in-reg LN2 -> FFN -> out=e_out.
// EDGE=false: X=wVd.   Phases: h2 = node + X@Wo + bo -> in-reg LN2 -> FFN -> out.
// Everything between stays in registers/LDS; one read of X, one write of out.
// ---------------------------------------------------------------------------
template <bool EDGE>
__global__ __launch_bounds__(256, 2) void mega_k(
    const float* __restrict__ X, const float* __restrict__ resid, int M,
    const int* __restrict__ eidx, int E,
    const float* __restrict__ Qm, const float* __restrict__ Km,
    const short* __restrict__ WgT, const short* __restrict__ WoT,
    const short* __restrict__ W1T, const short* __restrict__ W2T,
    const float* __restrict__ g1, const float* __restrict__ b1,
    const float* __restrict__ g2, const float* __restrict__ b2,
    const float* __restrict__ bo, float* __restrict__ wE,
    float* __restrict__ out)
{
    __shared__ short Als[128 * 72];
    __shared__ short Bls[128 * 72];
    __shared__ float redS[256];
    __shared__ float redQ[256];

    const int tid = threadIdx.x, l = tid & 63, w = tid >> 6;
    const int lanem = l & 15, laneq = l >> 4;
    const int rbase = blockIdx.x * 128;
    const int sm = tid >> 1, h = tid & 1;
    const int grow = rbase + sm;
    const bool rowok = grow < M;

    // per-lane col constants for epilogue/LN2
    float g2v[8], b2v[8], bov[8];
#pragma unroll
    for (int nt = 0; nt < 8; nt++) {
        const int gc = nt * 16 + lanem;
        g2v[nt] = g2[gc]; b2v[nt] = b2[gc]; bov[nt] = bo[gc];
    }

    float4v accS[2][8];  // EDGE: PE then score
    float4v e2a[2][8];   // proj acc -> e2/h2 (f32, lives to the end)
    float4v acc3[2][8];  // FFN second-GEMM acc

    // ---- Phase A+B (EDGE): LN1 stats + GEMM0 (PE = LN1(edgef) @ We) ----
    if constexpr (EDGE) {
        float s = 0.f, q = 0.f;
        const float* xr = X + (size_t)grow * 128 + h * 64;
#pragma unroll
        for (int i = 0; i < 16; i++) {
            float4 v = rowok ? *(const float4*)(xr + i * 4) : make_float4(0.f, 0.f, 0.f, 0.f);
            s += v.x + v.y + v.z + v.w;
            q += v.x * v.x + v.y * v.y + v.z * v.z + v.w * v.w;
        }
        redS[tid] = s; redQ[tid] = q;
        __syncthreads();
        float ts = redS[sm * 2] + redS[sm * 2 + 1];
        float tq = redQ[sm * 2] + redQ[sm * 2 + 1];
        float mu1 = ts * (1.f / 128.f);
        float var1 = tq * (1.f / 128.f) - mu1 * mu1;
        float rstd1 = rsqrtf(var1 + 1e-5f);

#pragma unroll
        for (int mt = 0; mt < 2; mt++)
#pragma unroll
            for (int nt = 0; nt < 8; nt++) accS[mt][nt] = (float4v){0.f, 0.f, 0.f, 0.f};

        for (int k0 = 0; k0 < 128; k0 += 64) {
            const int kb = k0 + h * 32;
            const float* xr2 = X + (size_t)grow * 128 + kb;
            float4 v[8];
#pragma unroll
            for (int i = 0; i < 8; i++)
                v[i] = rowok ? *(const float4*)(xr2 + i * 4) : make_float4(0.f, 0.f, 0.f, 0.f);
#pragma unroll
            for (int i = 0; i < 8; i++) {
                int c = kb + i * 4;
                float4 g4 = *(const float4*)(g1 + c);
                float4 b4 = *(const float4*)(b1 + c);
                v[i].x = (v[i].x - mu1) * rstd1 * g4.x + b4.x;
                v[i].y = (v[i].y - mu1) * rstd1 * g4.y + b4.y;
                v[i].z = (v[i].z - mu1) * rstd1 * g4.z + b4.z;
                v[i].w = (v[i].w - mu1) * rstd1 * g4.w + b4.w;
            }
            uint4* ad = (uint4*)(Als + sm * 72 + h * 32);
#pragma unroll
            for (int i = 0; i < 4; i++) {
                uint4 o;
                o.x = pack2(v[i * 2].x, v[i * 2].y);
                o.y = pack2(v[i * 2].z, v[i * 2].w);
                o.z = pack2(v[i * 2 + 1].x, v[i * 2 + 1].y);
                o.w = pack2(v[i * 2 + 1].z, v[i * 2 + 1].w);
                ad[i] = o;
            }
            stageB(Bls, WgT, 128, k0, sm, h);
            __syncthreads();
            mfma64s<72>(Als, Bls, w, lanem, laneq, accS);
            __syncthreads();
        }

        // ---- Phase C: score = clip(K[src]*Q[dst]/4)*PE (in acc), wE out ----
#pragma unroll
        for (int mt = 0; mt < 2; mt++)
#pragma unroll
            for (int r = 0; r < 4; r++) {
                const int row = w * 32 + mt * 16 + laneq * 4 + r;
                const int e = rbase + row;
                const bool ok = e < M;
                const int si = ok ? eidx[e] : 0;
                const int di = ok ? eidx[(size_t)E + e] : 0;
                const float* qr = Qm + (size_t)di * 128;
                const float* kr = Km + (size_t)si * 128;
                float hs[8];
#pragma unroll
                for (int nt = 0; nt < 8; nt++) {
                    const int gc = nt * 16 + lanem;
                    float sv = clip5(kr[gc] * qr[gc] * 0.25f) * accS[mt][nt][r];
                    accS[mt][nt][r] = sv;
                    hs[nt] = sv;
                }
#pragma unroll
                for (int nt = 0; nt < 8; nt++) {
                    hs[nt] += __shfl_xor(hs[nt], 1, 64);
                    hs[nt] += __shfl_xor(hs[nt], 2, 64);
                    hs[nt] += __shfl_xor(hs[nt], 4, 64);
                    hs[nt] += __shfl_xor(hs[nt], 8, 64);
                }
                if (lanem == 0 && ok) {
                    float4 wa, wb;
                    wa.x = __expf(clip5(hs[0])); wa.y = __expf(clip5(hs[1]));
                    wa.z = __expf(clip5(hs[2])); wa.w = __expf(clip5(hs[3]));
                    wb.x = __expf(clip5(hs[4])); wb.y = __expf(clip5(hs[5]));
                    wb.z = __expf(clip5(hs[6])); wb.w = __expf(clip5(hs[7]));
                    *(float4*)(wE + (size_t)e * 8) = wa;
                    *(float4*)(wE + (size_t)e * 8 + 4) = wb;
                }
            }
    }

    // ---- Phase D: proj GEMM (A = score [EDGE] or raw X [NODE]) @ WoT ----
#pragma unroll
    for (int mt = 0; mt < 2; mt++)
#pragma unroll
        for (int nt = 0; nt < 8; nt++) e2a[mt][nt] = (float4v){0.f, 0.f, 0.f, 0.f};

    for (int k0 = 0; k0 < 128; k0 += 64) {
        if constexpr (EDGE) {
            packA(Als, accS, k0 >> 4, w, lanem, laneq);
        } else {
            const int kb = k0 + h * 32;
            const float* xr2 = X + (size_t)grow * 128 + kb;
            float4 v[8];
#pragma unroll
            for (int i = 0; i < 8; i++)
                v[i] = rowok ? *(const float4*)(xr2 + i * 4) : make_float4(0.f, 0.f, 0.f, 0.f);
            uint4* ad = (uint4*)(Als + sm * 72 + h * 32);
#pragma unroll
            for (int i = 0; i < 4; i++) {
                uint4 o;
                o.x = pack2(v[i * 2].x, v[i * 2].y);
                o.y = pack2(v[i * 2].z, v[i * 2].w);
                o.z = pack2(v[i * 2 + 1].x, v[i * 2 + 1].y);
                o.w = pack2(v[i * 2 + 1].z, v[i * 2 + 1].w);
                ad[i] = o;
            }
        }
        stageB(Bls, WoT, 128, k0, sm, h);
        __syncthreads();
        mfma64s<72>(Als, Bls, w, lanem, laneq, e2a);
        __syncthreads();
    }

    // ---- Phase E: e2 = resid + proj + bo; in-register LN2 stats ----
    float mur[2][4], rsr[2][4];
#pragma unroll
    for (int mt = 0; mt < 2; mt++)
#pragma unroll
        for (int r = 0; r < 4; r++) {
            const int row = w * 32 + mt * 16 + laneq * 4 + r;
            const int gr = rbase + row;
            const bool ok = gr < M;
            float s = 0.f, q = 0.f;
#pragma unroll
            for (int nt = 0; nt < 8; nt++) {
                const int gc = nt * 16 + lanem;
                float rv = ok ? resid[(size_t)gr * 128 + gc] : 0.f;
                float x = rv + e2a[mt][nt][r] + bov[nt];
                e2a[mt][nt][r] = x;
                s += x; q += x * x;
            }
            s += __shfl_xor(s, 1, 64); q += __shfl_xor(q, 1, 64);
            s += __shfl_xor(s, 2, 64); q += __shfl_xor(q, 2, 64);
            s += __shfl_xor(s, 4, 64); q += __shfl_xor(q, 4, 64);
            s += __shfl_xor(s, 8, 64); q += __shfl_xor(q, 8, 64);
            float mu = s * (1.f / 128.f);
            float var = q * (1.f / 128.f) - mu * mu;
            mur[mt][r] = mu;
            rsr[mt][r] = rsqrtf(var + 1e-5f);
        }

    // ---- Phase F: FFN, two 128-col halves of W1; acc3 += silu(hn@W1h)@W2h ----
#pragma unroll
    for (int mt = 0; mt < 2; mt++)
#pragma unroll
        for (int nt = 0; nt < 8; nt++) acc3[mt][nt] = (float4v){0.f, 0.f, 0.f, 0.f};

    for (int hh = 0; hh < 2; hh++) {
        float4v acc2[2][8];
#pragma unroll
        for (int mt = 0; mt < 2; mt++)
#pragma unroll
            for (int nt = 0; nt < 8; nt++) acc2[mt][nt] = (float4v){0.f, 0.f, 0.f, 0.f};
        const short* w1b = W1T + (size_t)hh * 16384;
        for (int k0 = 0; k0 < 128; k0 += 64) {
            const int ntb = k0 >> 4;
            // pack hn = LN2(e2) cols [k0, k0+64)
#pragma unroll
            for (int mt = 0; mt < 2; mt++)
#pragma unroll
                for (int r = 0; r < 4; r++) {
                    const int row = w * 32 + mt * 16 + laneq * 4 + r;
                    const float muv = mur[mt][r], rv = rsr[mt][r];
#pragma unroll
                    for (int nt0 = 0; nt0 < 4; nt0++) {
                        const int nt = ntb + nt0;
                        float hnv = (e2a[mt][nt][r] - muv) * rv * g2v[nt] + b2v[nt];
                        Als[row * 72 + nt0 * 16 + lanem] = (short)f2bf(hnv);
                    }
                }
            stageB(Bls, w1b, 128, k0, sm, h);
            __syncthreads();
            mfma64s<72>(Als, Bls, w, lanem, laneq, acc2);
            __syncthreads();
        }
        // silu
#pragma unroll
        for (int mt = 0; mt < 2; mt++)
#pragma unroll
            for (int nt = 0; nt < 8; nt++)
#pragma unroll
                for (int r = 0; r < 4; r++) acc2[mt][nt][r] = silu_f(acc2[mt][nt][r]);
        // t @ W2 slice
        for (int k0 = 0; k0 < 128; k0 += 64) {
            packA(Als, acc2, k0 >> 4, w, lanem, laneq);
            stageB(Bls, W2T, 256, hh * 128 + k0, sm, h);
            __syncthreads();
            mfma64s<72>(Als, Bls, w, lanem, laneq, acc3);
            __syncthreads();
        }
    }

    // ---- Phase H: out = e2 + ffn ----
#pragma unroll
    for (int mt = 0; mt < 2; mt++)
#pragma unroll
        for (int nt = 0; nt < 8; nt++) {
            const int gc = nt * 16 + lanem;
#pragma unroll
            for (int r = 0; r < 4; r++) {
                const int gr = rbase + w * 32 + mt * 16 + laneq * 4 + r;
                if (gr < M) out[(size_t)gr * 128 + gc] = e2a[mt][nt][r] + acc3[mt][nt][r];
            }
        }
}

// ---------------------------------------------------------------------------
// CSR-by-dst build: count -> 2-level exclusive scan -> scatter (src,eid)
// ---------------------------------------------------------------------------
__global__ __launch_bounds__(256) void count_k(
    const int* __restrict__ eidx, int* __restrict__ deg, int E)
{
    int e = blockIdx.x * 256 + threadIdx.x;
    if (e < E) atomicAdd(&deg[eidx[(size_t)E + e]], 1);
}

__global__ __launch_bounds__(256) void scan_part_k(
    const int* __restrict__ deg, int* __restrict__ psum, int Nn)
{
    __shared__ int red[256];
    int i = blockIdx.x * 256 + threadIdx.x;
    red[threadIdx.x] = (i < Nn) ? deg[i] : 0;
    __syncthreads();
    for (int s = 128; s > 0; s >>= 1) {
        if (threadIdx.x < s) red[threadIdx.x] += red[threadIdx.x + s];
        __syncthreads();
    }
    if (threadIdx.x == 0) psum[blockIdx.x] = red[0];
}

__global__ __launch_bounds__(1024) void scan_mid_k(int* __restrict__ psum, int P)
{
    __shared__ int sm[1024];
    int t = threadIdx.x;
    int v = (t < P) ? psum[t] : 0;
    sm[t] = v;
    __syncthreads();
    for (int ofs = 1; ofs < 1024; ofs <<= 1) {
        int x = sm[t];
        if (t >= ofs) x += sm[t - ofs];
        __syncthreads();
        sm[t] = x;
        __syncthreads();
    }
    if (t < P) psum[t] = sm[t] - v;  // exclusive
}

__global__ __launch_bounds__(256) void scan_fin_k(
    int* __restrict__ deg_cur, const int* __restrict__ psum,
    int* __restrict__ rs, int Nn)
{
    __shared__ int sm[256];
    int i = blockIdx.x * 256 + threadIdx.x;
    int t = threadIdx.x;
    int v = (i < Nn) ? deg_cur[i] : 0;
    sm[t] = v;
    __syncthreads();
    for (int ofs = 1; ofs < 256; ofs <<= 1) {
        int x = sm[t];
        if (t >= ofs) x += sm[t - ofs];
        __syncthreads();
        sm[t] = x;
        __syncthreads();
    }
    if (i < Nn) {
        int excl = sm[t] - v + psum[blockIdx.x];
        rs[i] = excl;
        deg_cur[i] = excl;            // cursor for scatter
        if (i == Nn - 1) rs[Nn] = excl + v;
    }
}

__global__ __launch_bounds__(256) void scatter_k(
    const int* __restrict__ eidx, int* __restrict__ cur,
    int2* __restrict__ csr, int E)
{
    int e = blockIdx.x * 256 + threadIdx.x;
    if (e >= E) return;
    int d = eidx[(size_t)E + e];
    int pos = atomicAdd(&cur[d], 1);
    csr[pos] = make_int2(eidx[e], e);  // (src, eid)
}

// ---------------------------------------------------------------------------
// Node aggregation: per dst node, sum w*V[src] and z over its CSR edge list,
// write wV/(z+1e-6). 32 lanes/node, register accumulation, no atomics.
// ---------------------------------------------------------------------------
__global__ __launch_bounds__(256) void agg_k(
    const float* __restrict__ V, const float* __restrict__ wE,
    const int2* __restrict__ csr, const int* __restrict__ rs,
    float* __restrict__ out, int Nn)
{
    int n = blockIdx.x * 8 + (threadIdx.x >> 5);
    if (n >= Nn) return;
    int lane = threadIdx.x & 31;
    int h = lane >> 2;
    int b = rs[n], eend = rs[n + 1];
    float ax = 0.f, ay = 0.f, az = 0.f, aw = 0.f, zs = 0.f;
    for (int i = b; i < eend; i++) {
        int2 pr = csr[i];
        float w = wE[(size_t)pr.y * 8 + h];
        float4 vv = *(const float4*)(V + (size_t)pr.x * 128 + (size_t)lane * 4);
        ax += w * vv.x; ay += w * vv.y; az += w * vv.z; aw += w * vv.w;
        zs += w;
    }
    float rz = 1.f / (zs + 1e-6f);
    *(float4*)(out + (size_t)n * 128 + (size_t)lane * 4) =
        make_float4(ax * rz, ay * rz, az * rz, aw * rz);
}

// ---------------------------------------------------------------------------
extern "C" void kernel_launch(void* const* d_in, const int* in_sizes, int n_in,
                              void* d_out, int out_size, void* d_ws, size_t ws_size,
                              hipStream_t stream)
{
    const float* node  = (const float*)d_in[0];
    const float* edgef = (const float*)d_in[1];
    const int*   eidx  = (const int*)d_in[2];
    const float* Wq = (const float*)d_in[3];
    const float* Wk = (const float*)d_in[4];
    const float* Wv = (const float*)d_in[5];
    const float* We = (const float*)d_in[6];
    const float* Wo_n = (const float*)d_in[7];
    const float* bo_n = (const float*)d_in[8];
    const float* Wo_e = (const float*)d_in[9];
    const float* bo_e = (const float*)d_in[10];
    const float* W1n = (const float*)d_in[11];
    const float* W2n = (const float*)d_in[12];
    const float* W1e = (const float*)d_in[13];
    const float* W2e = (const float*)d_in[14];
    const float* g1n = (const float*)d_in[15];
    const float* b1n = (const float*)d_in[16];
    const float* g1e = (const float*)d_in[17];
    const float* b1e = (const float*)d_in[18];
    const float* g2n = (const float*)d_in[19];
    const float* b2n = (const float*)d_in[20];
    const float* g2e = (const float*)d_in[21];
    const float* b2e = (const float*)d_in[22];

    const int N = in_sizes[0] / 128;
    const int E = in_sizes[1] / 128;
    float* outn = (float*)d_out;                    // node out
    float* oute = (float*)d_out + (size_t)N * 128;  // edge out

    // ---- workspace: bf16 transposed weights first, then fp32/int buffers ----
    unsigned short* wts = (unsigned short*)d_ws;
    unsigned short* WqT  = wts;            // 128x128
    unsigned short* WkT  = wts + 16384;
    unsigned short* WvT  = wts + 32768;
    unsigned short* WeT  = wts + 49152;
    unsigned short* WonT = wts + 65536;
    unsigned short* WoeT = wts + 81920;
    unsigned short* W1nT = wts + 98304;    // 256x128
    unsigned short* W1eT = wts + 131072;   // 256x128
    unsigned short* W2nT = wts + 163840;   // 128x256
    unsigned short* W2eT = wts + 196608;   // 128x256  (end: 229376 shorts)
    float* p = (float*)(wts + 229376);
    float* Qb  = p; p += (size_t)N * 128;
    float* Kb  = p; p += (size_t)N * 128;
    float* Vb  = p; p += (size_t)N * 128;
    float* wVd = p; p += (size_t)N * 128;   // divided aggregation result
    float* wEb = p; p += (size_t)E * 8;     // per-edge per-head weights
    int* rs   = (int*)p;                    // rowstart, N+1
    int* cur  = rs + (N + 1);               // degree / scatter cursor, N
    int* psum = cur + N;                    // partial sums, up to 1024
    int* csr_i = psum + 1024;
    csr_i = (int*)(((uintptr_t)csr_i + 15) & ~(uintptr_t)15);
    int2* csr = (int2*)csr_i;               // E entries (src, eid)

    // ---- weight conversion (one launch, 10 matrices) ----
    {
        WPack pk;
        pk.d[0] = {Wq,   WqT,  128, 128}; pk.d[1] = {Wk,   WkT,  128, 128};
        pk.d[2] = {Wv,   WvT,  128, 128}; pk.d[3] = {We,   WeT,  128, 128};
        pk.d[4] = {Wo_n, WonT, 128, 128}; pk.d[5] = {Wo_e, WoeT, 128, 128};
        pk.d[6] = {W1n,  W1nT, 128, 256}; pk.d[7] = {W1e,  W1eT, 128, 256};
        pk.d[8] = {W2n,  W2nT, 256, 128}; pk.d[9] = {W2e,  W2eT, 256, 128};
        cvt_all_k<<<dim3(128, 10), 256, 0, stream>>>(pk);
    }

    dim3 blk(256);
    const int rbN = (N + 127) / 128;
    const int rbE = (E + 127) / 128;
    const int P = (N + 255) / 256;

    // ---- CSR-by-dst build ----
    hipMemsetAsync(cur, 0, (size_t)N * sizeof(int), stream);
    count_k<<<(E + 255) / 256, blk, 0, stream>>>(eidx, cur, E);
    scan_part_k<<<P, blk, 0, stream>>>(cur, psum, N);
    scan_mid_k<<<1, 1024, 0, stream>>>(psum, P);
    scan_fin_k<<<P, blk, 0, stream>>>(cur, psum, rs, N);
    scatter_k<<<(E + 255) / 256, blk, 0, stream>>>(eidx, cur, csr, E);

    // 1) Q/K/V = LN1(node) @ {Wq,Wk,Wv} (one fused kernel)
    qkv_k<<<rbN, blk, 0, stream>>>(node, N, (const short*)WqT, (const short*)WkT,
                                   (const short*)WvT, g1n, b1n, Qb, Kb, Vb);

    // 2) EDGE MEGA: LN1(edge)->PE->score->wE->e2->LN2->FFN->e_out
    mega_k<true><<<rbE, blk, 0, stream>>>(
        edgef, edgef, E, eidx, E, Qb, Kb,
        (const short*)WeT, (const short*)WoeT, (const short*)W1eT, (const short*)W2eT,
        g1e, b1e, g2e, b2e, bo_e, wEb, oute);

    // 3) node aggregation via CSR: wVd = segsum(w*V[src]) / (segsum(w)+1e-6)
    agg_k<<<(N + 7) / 8, blk, 0, stream>>>(Vb, wEb, csr, rs, wVd, N);

    // 4) NODE MEGA: h2 = node + wVd@Wo_n + bo_n -> LN2 -> FFN -> h_out
    mega_k<false><<<rbN, blk, 0, stream>>>(
        wVd, node, N, nullptr, 0, nullptr, nullptr,
        nullptr, (const short*)WonT, (const short*)W1nT, (const short*)W2nT,
        nullptr, nullptr, g2n, b2n, bo_n, nullptr, outn);
}

// Round 3
// 899.470 us; speedup vs baseline: 2.4996x; 1.2258x over previous
//
#include <hip/hip_runtime.h>
#include <cstdint>
#include <cstddef>

#define DEVI __device__ __forceinline__

typedef __attribute__((ext_vector_type(8))) short short8;   // 8 bf16 = 4 VGPRs
typedef __attribute__((ext_vector_type(4))) float float4v;  // MFMA acc

DEVI float silu_f(float x) { return x / (1.f + __expf(-x)); }
DEVI float clip5(float x) { return fminf(fmaxf(x, -5.f), 5.f); }

DEVI unsigned short f2bf(float f) {
    union { float f; unsigned u; } x{f};
    unsigned r = x.u + 0x7FFF + ((x.u >> 16) & 1);  // RNE
    return (unsigned short)(r >> 16);
}
DEVI unsigned pack2(float a, float b) {
    return (unsigned)f2bf(a) | ((unsigned)f2bf(b) << 16);
}

// ---------------------------------------------------------------------------
// Weight pre-convert: src[K][N] fp32 -> dst[N][K] bf16 (transposed), 10 mats.
// ---------------------------------------------------------------------------
struct WDesc { const float* src; unsigned short* dst; int K; int N; };
struct WPack { WDesc d[10]; };

__global__ __launch_bounds__(256) void cvt_all_k(WPack p) {
    const WDesc w = p.d[blockIdx.y];
    const int total = w.K * w.N;
    const int ln = (w.N == 256) ? 8 : 7;  // N is 128 or 256
    const int nm = w.N - 1;
    for (int idx = blockIdx.x * 256 + threadIdx.x; idx < total; idx += gridDim.x * 256) {
        int k = idx >> ln, n = idx & nm;
        w.dst[(size_t)n * w.K + k] = f2bf(w.src[idx]);
    }
}

// ---------------------------------------------------------------------------
// Shared MFMA helpers (4-wave block, M-tile 128, N 128, per-wave 32x128).
// Acc layout: row = w*32 + mt*16 + laneq*4 + r, col = nt*16 + lanem.
// ---------------------------------------------------------------------------
template <int LDA>
DEVI void mfma64s(const short* A, const short* B, int w, int lanem, int laneq,
                  float4v acc[2][8]) {
#pragma unroll
    for (int s = 0; s < 2; s++) {
        const int ko = s * 32 + laneq * 8;
        short8 bfr[8];
#pragma unroll
        for (int nt = 0; nt < 8; nt++)
            bfr[nt] = *(const short8*)(B + (nt * 16 + lanem) * 72 + ko);
#pragma unroll
        for (int mt = 0; mt < 2; mt++) {
            short8 af = *(const short8*)(A + (w * 32 + mt * 16 + lanem) * LDA + ko);
#pragma unroll
            for (int nt = 0; nt < 8; nt++)
                acc[mt][nt] = __builtin_amdgcn_mfma_f32_16x16x32_bf16(
                    af, bfr[nt], acc[mt][nt], 0, 0, 0);
        }
    }
}

DEVI void stageB(short* Bls, const short* WT, int ldw, int koff, int sm, int h) {
    const uint4* bs = (const uint4*)(WT + (size_t)sm * ldw + koff + h * 32);
    uint4* bd = (uint4*)(Bls + sm * 72 + h * 32);
#pragma unroll
    for (int i = 0; i < 4; i++) bd[i] = bs[i];
}

// pack acc-fragment cols [ntb*16, ntb*16+64) -> A LDS (cols 0..63, stride LDA)
// ntb MUST be compile-time (callers unroll) so acc stays in VGPRs.
template <int LDA>
DEVI void packA(short* Als, const float4v a[2][8], int ntb, int w, int lanem, int laneq) {
#pragma unroll
    for (int mt = 0; mt < 2; mt++)
#pragma unroll
        for (int r = 0; r < 4; r++) {
            const int row = w * 32 + mt * 16 + laneq * 4 + r;
#pragma unroll
            for (int nt0 = 0; nt0 < 4; nt0++)
                Als[row * LDA + nt0 * 16 + lanem] = (short)f2bf(a[mt][ntb + nt0][r]);
        }
}

// ---------------------------------------------------------------------------
// QKV fused: stage LN1(node) once -> Xls, then 3 GEMMs (Wq,Wk,Wv).
// ---------------------------------------------------------------------------
__global__ __launch_bounds__(256, 2) void qkv_k(
    const float* __restrict__ X, int M,
    const short* __restrict__ W0, const short* __restrict__ W1, const short* __restrict__ W2,
    const float* __restrict__ g, const float* __restrict__ b,
    float* __restrict__ o0, float* __restrict__ o1, float* __restrict__ o2)
{
    __shared__ short Xls[128 * 136];
    __shared__ short Bls[128 * 72];
    __shared__ float redS[256];
    __shared__ float redQ[256];

    const int tid = threadIdx.x, l = tid & 63, w = tid >> 6;
    const int lanem = l & 15, laneq = l >> 4;
    const int rbase = blockIdx.x * 128;
    const int sm = tid >> 1, h = tid & 1;
    const int grow = rbase + sm;
    const bool rowok = grow < M;

    // LN stats + stage (single X read: keep row-half in regs)
    {
        float4 v[16];
        const float* xr = X + (size_t)grow * 128 + h * 64;
        float s = 0.f, q = 0.f;
#pragma unroll
        for (int i = 0; i < 16; i++) {
            v[i] = rowok ? *(const float4*)(xr + i * 4) : make_float4(0.f, 0.f, 0.f, 0.f);
            s += v[i].x + v[i].y + v[i].z + v[i].w;
            q += v[i].x * v[i].x + v[i].y * v[i].y + v[i].z * v[i].z + v[i].w * v[i].w;
        }
        redS[tid] = s; redQ[tid] = q;
        __syncthreads();
        float ts = redS[sm * 2] + redS[sm * 2 + 1];
        float tq = redQ[sm * 2] + redQ[sm * 2 + 1];
        float mu = ts * (1.f / 128.f);
        float var = tq * (1.f / 128.f) - mu * mu;
        float rstd = rsqrtf(var + 1e-5f);
#pragma unroll
        for (int i = 0; i < 16; i++) {
            int c = h * 64 + i * 4;
            float4 g4 = *(const float4*)(g + c);
            float4 b4 = *(const float4*)(b + c);
            v[i].x = (v[i].x - mu) * rstd * g4.x + b4.x;
            v[i].y = (v[i].y - mu) * rstd * g4.y + b4.y;
            v[i].z = (v[i].z - mu) * rstd * g4.z + b4.z;
            v[i].w = (v[i].w - mu) * rstd * g4.w + b4.w;
        }
        uint4* xd = (uint4*)(Xls + sm * 136 + h * 64);
#pragma unroll
        for (int i = 0; i < 8; i++) {
            uint4 o;
            o.x = pack2(v[i * 2].x, v[i * 2].y);
            o.y = pack2(v[i * 2].z, v[i * 2].w);
            o.z = pack2(v[i * 2 + 1].x, v[i * 2 + 1].y);
            o.w = pack2(v[i * 2 + 1].z, v[i * 2 + 1].w);
            xd[i] = o;
        }
    }
    __syncthreads();

    const short* Ws[3] = {W0, W1, W2};
    float* outs[3] = {o0, o1, o2};
#pragma unroll
    for (int j = 0; j < 3; j++) {
        float4v acc[2][8];
#pragma unroll
        for (int mt = 0; mt < 2; mt++)
#pragma unroll
            for (int nt = 0; nt < 8; nt++) acc[mt][nt] = (float4v){0.f, 0.f, 0.f, 0.f};
#pragma unroll
        for (int k0 = 0; k0 < 128; k0 += 64) {
            stageB(Bls, Ws[j], 128, k0, sm, h);
            __syncthreads();
            mfma64s<136>(Xls + k0, Bls, w, lanem, laneq, acc);
            __syncthreads();
        }
        float* oj = outs[j];
#pragma unroll
        for (int mt = 0; mt < 2; mt++)
#pragma unroll
            for (int nt = 0; nt < 8; nt++) {
                const int gc = nt * 16 + lanem;
#pragma unroll
                for (int r = 0; r < 4; r++) {
                    int gr = rbase + w * 32 + mt * 16 + laneq * 4 + r;
                    if (gr < M) oj[(size_t)gr * 128 + gc] = acc[mt][nt][r];
                }
            }
    }
}

// ---------------------------------------------------------------------------
// MEGA kernel.
// EDGE=true : X=edgef. LN1 -> PE=@We -> score(clip(QK/4)*PE, wE out)
//             -> e2 = edgef + score@Wo + bo -> in-reg LN2 -> FFN -> e_out.
// EDGE=false: X=wVd.   h2 = node + X@Wo + bo -> in-reg LN2 -> FFN -> h_out.
// All intermediates stay in registers/LDS. FFN GEMM2 accumulates into e2a.
// ---------------------------------------------------------------------------
template <bool EDGE>
__global__ __launch_bounds__(256, 2) void mega_k(
    const float* __restrict__ X, const float* __restrict__ resid, int M,
    const int* __restrict__ eidx, int E,
    const float* __restrict__ Qm, const float* __restrict__ Km,
    const short* __restrict__ WgT, const short* __restrict__ WoT,
    const short* __restrict__ W1T, const short* __restrict__ W2T,
    const float* __restrict__ g1, const float* __restrict__ b1,
    const float* __restrict__ g2, const float* __restrict__ b2,
    const float* __restrict__ bo, float* __restrict__ wE,
    float* __restrict__ out)
{
    __shared__ short Xls[128 * 136];   // A operand / staged X / staged hn
    __shared__ short Bls[128 * 72];
    __shared__ float redS[256];
    __shared__ float redQ[256];

    const int tid = threadIdx.x, l = tid & 63, w = tid >> 6;
    const int lanem = l & 15, laneq = l >> 4;
    const int rbase = blockIdx.x * 128;
    const int sm = tid >> 1, h = tid & 1;
    const int grow = rbase + sm;
    const bool rowok = grow < M;

    float4v accS[2][8];  // EDGE: PE then score
    float4v e2a[2][8];   // proj acc -> e2/h2 -> final out (GEMM2 accumulates)

    // ---- Phase A+B (EDGE): LN1 (single X read) + GEMM0 (PE = LN1(X) @ We) ----
    if constexpr (EDGE) {
        {
            float4 v[16];
            const float* xr = X + (size_t)grow * 128 + h * 64;
            float s = 0.f, q = 0.f;
#pragma unroll
            for (int i = 0; i < 16; i++) {
                v[i] = rowok ? *(const float4*)(xr + i * 4) : make_float4(0.f, 0.f, 0.f, 0.f);
                s += v[i].x + v[i].y + v[i].z + v[i].w;
                q += v[i].x * v[i].x + v[i].y * v[i].y + v[i].z * v[i].z + v[i].w * v[i].w;
            }
            redS[tid] = s; redQ[tid] = q;
            __syncthreads();
            float ts = redS[sm * 2] + redS[sm * 2 + 1];
            float tq = redQ[sm * 2] + redQ[sm * 2 + 1];
            float mu1 = ts * (1.f / 128.f);
            float var1 = tq * (1.f / 128.f) - mu1 * mu1;
            float rstd1 = rsqrtf(var1 + 1e-5f);
#pragma unroll
            for (int i = 0; i < 16; i++) {
                int c = h * 64 + i * 4;
                float4 g4 = *(const float4*)(g1 + c);
                float4 b4 = *(const float4*)(b1 + c);
                v[i].x = (v[i].x - mu1) * rstd1 * g4.x + b4.x;
                v[i].y = (v[i].y - mu1) * rstd1 * g4.y + b4.y;
                v[i].z = (v[i].z - mu1) * rstd1 * g4.z + b4.z;
                v[i].w = (v[i].w - mu1) * rstd1 * g4.w + b4.w;
            }
            uint4* xd = (uint4*)(Xls + sm * 136 + h * 64);
#pragma unroll
            for (int i = 0; i < 8; i++) {
                uint4 o;
                o.x = pack2(v[i * 2].x, v[i * 2].y);
                o.y = pack2(v[i * 2].z, v[i * 2].w);
                o.z = pack2(v[i * 2 + 1].x, v[i * 2 + 1].y);
                o.w = pack2(v[i * 2 + 1].z, v[i * 2 + 1].w);
                xd[i] = o;
            }
        }

#pragma unroll
        for (int mt = 0; mt < 2; mt++)
#pragma unroll
            for (int nt = 0; nt < 8; nt++) accS[mt][nt] = (float4v){0.f, 0.f, 0.f, 0.f};

#pragma unroll
        for (int k0 = 0; k0 < 128; k0 += 64) {
            stageB(Bls, WgT, 128, k0, sm, h);
            __syncthreads();
            mfma64s<136>(Xls + k0, Bls, w, lanem, laneq, accS);
            __syncthreads();
        }

        // ---- Phase C: score = clip(K[src]*Q[dst]/4)*PE (in acc), wE out ----
#pragma unroll
        for (int mt = 0; mt < 2; mt++)
#pragma unroll
            for (int r = 0; r < 4; r++) {
                const int row = w * 32 + mt * 16 + laneq * 4 + r;
                const int e = rbase + row;
                const bool ok = e < M;
                const int si = ok ? eidx[e] : 0;
                const int di = ok ? eidx[(size_t)E + e] : 0;
                const float* qr = Qm + (size_t)di * 128;
                const float* kr = Km + (size_t)si * 128;
                float hs[8];
#pragma unroll
                for (int nt = 0; nt < 8; nt++) {
                    const int gc = nt * 16 + lanem;
                    float sv = clip5(kr[gc] * qr[gc] * 0.25f) * accS[mt][nt][r];
                    accS[mt][nt][r] = sv;
                    hs[nt] = sv;
                }
#pragma unroll
                for (int nt = 0; nt < 8; nt++) {
                    hs[nt] += __shfl_xor(hs[nt], 1, 64);
                    hs[nt] += __shfl_xor(hs[nt], 2, 64);
                    hs[nt] += __shfl_xor(hs[nt], 4, 64);
                    hs[nt] += __shfl_xor(hs[nt], 8, 64);
                }
                if (lanem == 0 && ok) {
                    float4 wa, wb;
                    wa.x = __expf(clip5(hs[0])); wa.y = __expf(clip5(hs[1]));
                    wa.z = __expf(clip5(hs[2])); wa.w = __expf(clip5(hs[3]));
                    wb.x = __expf(clip5(hs[4])); wb.y = __expf(clip5(hs[5]));
                    wb.z = __expf(clip5(hs[6])); wb.w = __expf(clip5(hs[7]));
                    *(float4*)(wE + (size_t)e * 8) = wa;
                    *(float4*)(wE + (size_t)e * 8 + 4) = wb;
                }
            }
    } else {
        // NODE: stage raw X once into Xls (both halves)
#pragma unroll
        for (int k0 = 0; k0 < 128; k0 += 64) {
            const int kb = k0 + h * 32;
            const float* xr2 = X + (size_t)grow * 128 + kb;
            float4 v[8];
#pragma unroll
            for (int i = 0; i < 8; i++)
                v[i] = rowok ? *(const float4*)(xr2 + i * 4) : make_float4(0.f, 0.f, 0.f, 0.f);
            uint4* ad = (uint4*)(Xls + sm * 136 + kb);
#pragma unroll
            for (int i = 0; i < 4; i++) {
                uint4 o;
                o.x = pack2(v[i * 2].x, v[i * 2].y);
                o.y = pack2(v[i * 2].z, v[i * 2].w);
                o.z = pack2(v[i * 2 + 1].x, v[i * 2 + 1].y);
                o.w = pack2(v[i * 2 + 1].z, v[i * 2 + 1].w);
                ad[i] = o;
            }
        }
    }

    // ---- Phase D: proj GEMM (A = score [EDGE] or staged X [NODE]) @ WoT ----
#pragma unroll
    for (int mt = 0; mt < 2; mt++)
#pragma unroll
        for (int nt = 0; nt < 8; nt++) e2a[mt][nt] = (float4v){0.f, 0.f, 0.f, 0.f};

#pragma unroll
    for (int k0 = 0; k0 < 128; k0 += 64) {
        if constexpr (EDGE) {
            packA<136>(Xls, accS, k0 >> 4, w, lanem, laneq);  // cols 0..63
        }
        stageB(Bls, WoT, 128, k0, sm, h);
        __syncthreads();
        if constexpr (EDGE)
            mfma64s<136>(Xls, Bls, w, lanem, laneq, e2a);
        else
            mfma64s<136>(Xls + k0, Bls, w, lanem, laneq, e2a);
        __syncthreads();
    }

    // ---- Phase E: e2 = resid + proj + bo; in-register LN2 stats ----
    float mur[2][4], rsr[2][4];
#pragma unroll
    for (int mt = 0; mt < 2; mt++)
#pragma unroll
        for (int r = 0; r < 4; r++) {
            const int row = w * 32 + mt * 16 + laneq * 4 + r;
            const int gr = rbase + row;
            const bool ok = gr < M;
            float s = 0.f, q = 0.f;
#pragma unroll
            for (int nt = 0; nt < 8; nt++) {
                const int gc = nt * 16 + lanem;
                float rv = ok ? resid[(size_t)gr * 128 + gc] : 0.f;
                float x = rv + e2a[mt][nt][r] + bo[gc];
                e2a[mt][nt][r] = x;
                s += x; q += x * x;
            }
            s += __shfl_xor(s, 1, 64); q += __shfl_xor(q, 1, 64);
            s += __shfl_xor(s, 2, 64); q += __shfl_xor(q, 2, 64);
            s += __shfl_xor(s, 4, 64); q += __shfl_xor(q, 4, 64);
            s += __shfl_xor(s, 8, 64); q += __shfl_xor(q, 8, 64);
            float mu = s * (1.f / 128.f);
            float var = q * (1.f / 128.f) - mu * mu;
            mur[mt][r] = mu;
            rsr[mt][r] = rsqrtf(var + 1e-5f);
        }

    // ---- Phase F: pack hn = LN2(e2) fully into Xls (frees LN state) ----
#pragma unroll
    for (int mt = 0; mt < 2; mt++)
#pragma unroll
        for (int r = 0; r < 4; r++) {
            const int row = w * 32 + mt * 16 + laneq * 4 + r;
            const float muv = mur[mt][r], rv = rsr[mt][r];
#pragma unroll
            for (int nt = 0; nt < 8; nt++) {
                const int gc = nt * 16 + lanem;
                float hnv = (e2a[mt][nt][r] - muv) * rv * g2[gc] + b2[gc];
                Xls[row * 136 + gc] = (short)f2bf(hnv);
            }
        }

    // ---- GEMM1 both halves: acc2[hh] = hn @ W1half ----
    float4v acc2[2][2][8];
#pragma unroll
    for (int hh = 0; hh < 2; hh++)
#pragma unroll
        for (int mt = 0; mt < 2; mt++)
#pragma unroll
            for (int nt = 0; nt < 8; nt++) acc2[hh][mt][nt] = (float4v){0.f, 0.f, 0.f, 0.f};

#pragma unroll
    for (int hh = 0; hh < 2; hh++) {
        const short* w1b = W1T + hh * 16384;
#pragma unroll
        for (int k0 = 0; k0 < 128; k0 += 64) {
            stageB(Bls, w1b, 128, k0, sm, h);
            __syncthreads();
            mfma64s<136>(Xls + k0, Bls, w, lanem, laneq, acc2[hh]);
            __syncthreads();
        }
    }

    // silu
#pragma unroll
    for (int hh = 0; hh < 2; hh++)
#pragma unroll
        for (int mt = 0; mt < 2; mt++)
#pragma unroll
            for (int nt = 0; nt < 8; nt++)
#pragma unroll
                for (int r = 0; r < 4; r++)
                    acc2[hh][mt][nt][r] = silu_f(acc2[hh][mt][nt][r]);

    // ---- GEMM2: e2a += silu(t) @ W2 (accumulate into residual acc) ----
#pragma unroll
    for (int hh = 0; hh < 2; hh++) {
#pragma unroll
        for (int k0 = 0; k0 < 128; k0 += 64) {
            packA<136>(Xls, acc2[hh], k0 >> 4, w, lanem, laneq);  // cols 0..63
            stageB(Bls, W2T, 256, hh * 128 + k0, sm, h);
            __syncthreads();
            mfma64s<136>(Xls, Bls, w, lanem, laneq, e2a);
            __syncthreads();
        }
    }

    // ---- epilogue: out = e2a ----
#pragma unroll
    for (int mt = 0; mt < 2; mt++)
#pragma unroll
        for (int nt = 0; nt < 8; nt++) {
            const int gc = nt * 16 + lanem;
#pragma unroll
            for (int r = 0; r < 4; r++) {
                const int gr = rbase + w * 32 + mt * 16 + laneq * 4 + r;
                if (gr < M) out[(size_t)gr * 128 + gc] = e2a[mt][nt][r];
            }
        }
}

// ---------------------------------------------------------------------------
// CSR-by-dst build: count -> 2-level exclusive scan -> scatter (src,eid)
// ---------------------------------------------------------------------------
__global__ __launch_bounds__(256) void count_k(
    const int* __restrict__ eidx, int* __restrict__ deg, int E)
{
    int e = blockIdx.x * 256 + threadIdx.x;
    if (e < E) atomicAdd(&deg[eidx[(size_t)E + e]], 1);
}

__global__ __launch_bounds__(256) void scan_part_k(
    const int* __restrict__ deg, int* __restrict__ psum, int Nn)
{
    __shared__ int red[256];
    int i = blockIdx.x * 256 + threadIdx.x;
    red[threadIdx.x] = (i < Nn) ? deg[i] : 0;
    __syncthreads();
    for (int s = 128; s > 0; s >>= 1) {
        if (threadIdx.x < s) red[threadIdx.x] += red[threadIdx.x + s];
        __syncthreads();
    }
    if (threadIdx.x == 0) psum[blockIdx.x] = red[0];
}

__global__ __launch_bounds__(1024) void scan_mid_k(int* __restrict__ psum, int P)
{
    __shared__ int sm[1024];
    int t = threadIdx.x;
    int v = (t < P) ? psum[t] : 0;
    sm[t] = v;
    __syncthreads();
    for (int ofs = 1; ofs < 1024; ofs <<= 1) {
        int x = sm[t];
        if (t >= ofs) x += sm[t - ofs];
        __syncthreads();
        sm[t] = x;
        __syncthreads();
    }
    if (t < P) psum[t] = sm[t] - v;  // exclusive
}

__global__ __launch_bounds__(256) void scan_fin_k(
    int* __restrict__ deg_cur, const int* __restrict__ psum,
    int* __restrict__ rs, int Nn)
{
    __shared__ int sm[256];
    int i = blockIdx.x * 256 + threadIdx.x;
    int t = threadIdx.x;
    int v = (i < Nn) ? deg_cur[i] : 0;
    sm[t] = v;
    __syncthreads();
    for (int ofs = 1; ofs < 256; ofs <<= 1) {
        int x = sm[t];
        if (t >= ofs) x += sm[t - ofs];
        __syncthreads();
        sm[t] = x;
        __syncthreads();
    }
    if (i < Nn) {
        int excl = sm[t] - v + psum[blockIdx.x];
        rs[i] = excl;
        deg_cur[i] = excl;            // cursor for scatter
        if (i == Nn - 1) rs[Nn] = excl + v;
    }
}

__global__ __launch_bounds__(256) void scatter_k(
    const int* __restrict__ eidx, int* __restrict__ cur,
    int2* __restrict__ csr, int E)
{
    int e = blockIdx.x * 256 + threadIdx.x;
    if (e >= E) return;
    int d = eidx[(size_t)E + e];
    int pos = atomicAdd(&cur[d], 1);
    csr[pos] = make_int2(eidx[e], e);  // (src, eid)
}

// ---------------------------------------------------------------------------
// Node aggregation: per dst node, sum w*V[src] and z over its CSR edge list,
// write wV/(z+1e-6). 32 lanes/node, register accumulation, no atomics.
// ---------------------------------------------------------------------------
__global__ __launch_bounds__(256) void agg_k(
    const float* __restrict__ V, const float* __restrict__ wE,
    const int2* __restrict__ csr, const int* __restrict__ rs,
    float* __restrict__ out, int Nn)
{
    int n = blockIdx.x * 8 + (threadIdx.x >> 5);
    if (n >= Nn) return;
    int lane = threadIdx.x & 31;
    int h = lane >> 2;
    int b = rs[n], eend = rs[n + 1];
    float ax = 0.f, ay = 0.f, az = 0.f, aw = 0.f, zs = 0.f;
    for (int i = b; i < eend; i++) {
        int2 pr = csr[i];
        float w = wE[(size_t)pr.y * 8 + h];
        float4 vv = *(const float4*)(V + (size_t)pr.x * 128 + (size_t)lane * 4);
        ax += w * vv.x; ay += w * vv.y; az += w * vv.z; aw += w * vv.w;
        zs += w;
    }
    float rz = 1.f / (zs + 1e-6f);
    *(float4*)(out + (size_t)n * 128 + (size_t)lane * 4) =
        make_float4(ax * rz, ay * rz, az * rz, aw * rz);
}

// ---------------------------------------------------------------------------
extern "C" void kernel_launch(void* const* d_in, const int* in_sizes, int n_in,
                              void* d_out, int out_size, void* d_ws, size_t ws_size,
                              hipStream_t stream)
{
    const float* node  = (const float*)d_in[0];
    const float* edgef = (const float*)d_in[1];
    const int*   eidx  = (const int*)d_in[2];
    const float* Wq = (const float*)d_in[3];
    const float* Wk = (const float*)d_in[4];
    const float* Wv = (const float*)d_in[5];
    const float* We = (const float*)d_in[6];
    const float* Wo_n = (const float*)d_in[7];
    const float* bo_n = (const float*)d_in[8];
    const float* Wo_e = (const float*)d_in[9];
    const float* bo_e = (const float*)d_in[10];
    const float* W1n = (const float*)d_in[11];
    const float* W2n = (const float*)d_in[12];
    const float* W1e = (const float*)d_in[13];
    const float* W2e = (const float*)d_in[14];
    const float* g1n = (const float*)d_in[15];
    const float* b1n = (const float*)d_in[16];
    const float* g1e = (const float*)d_in[17];
    const float* b1e = (const float*)d_in[18];
    const float* g2n = (const float*)d_in[19];
    const float* b2n = (const float*)d_in[20];
    const float* g2e = (const float*)d_in[21];
    const float* b2e = (const float*)d_in[22];

    const int N = in_sizes[0] / 128;
    const int E = in_sizes[1] / 128;
    float* outn = (float*)d_out;                    // node out
    float* oute = (float*)d_out + (size_t)N * 128;  // edge out

    // ---- workspace: bf16 transposed weights first, then fp32/int buffers ----
    unsigned short* wts = (unsigned short*)d_ws;
    unsigned short* WqT  = wts;            // 128x128
    unsigned short* WkT  = wts + 16384;
    unsigned short* WvT  = wts + 32768;
    unsigned short* WeT  = wts + 49152;
    unsigned short* WonT = wts + 65536;
    unsigned short* WoeT = wts + 81920;
    unsigned short* W1nT = wts + 98304;    // 256x128
    unsigned short* W1eT = wts + 131072;   // 256x128
    unsigned short* W2nT = wts + 163840;   // 128x256
    unsigned short* W2eT = wts + 196608;   // 128x256  (end: 229376 shorts)
    float* p = (float*)(wts + 229376);
    float* Qb  = p; p += (size_t)N * 128;
    float* Kb  = p; p += (size_t)N * 128;
    float* Vb  = p; p += (size_t)N * 128;
    float* wVd = p; p += (size_t)N * 128;   // divided aggregation result
    float* wEb = p; p += (size_t)E * 8;     // per-edge per-head weights
    int* rs   = (int*)p;                    // rowstart, N+1
    int* cur  = rs + (N + 1);               // degree / scatter cursor, N
    int* psum = cur + N;                    // partial sums, up to 1024
    int* csr_i = psum + 1024;
    csr_i = (int*)(((uintptr_t)csr_i + 15) & ~(uintptr_t)15);
    int2* csr = (int2*)csr_i;               // E entries (src, eid)

    // ---- weight conversion (one launch, 10 matrices) ----
    {
        WPack pk;
        pk.d[0] = {Wq,   WqT,  128, 128}; pk.d[1] = {Wk,   WkT,  128, 128};
        pk.d[2] = {Wv,   WvT,  128, 128}; pk.d[3] = {We,   WeT,  128, 128};
        pk.d[4] = {Wo_n, WonT, 128, 128}; pk.d[5] = {Wo_e, WoeT, 128, 128};
        pk.d[6] = {W1n,  W1nT, 128, 256}; pk.d[7] = {W1e,  W1eT, 128, 256};
        pk.d[8] = {W2n,  W2nT, 256, 128}; pk.d[9] = {W2e,  W2eT, 256, 128};
        cvt_all_k<<<dim3(128, 10), 256, 0, stream>>>(pk);
    }

    dim3 blk(256);
    const int rbN = (N + 127) / 128;
    const int rbE = (E + 127) / 128;
    const int P = (N + 255) / 256;

    // ---- CSR-by-dst build ----
    hipMemsetAsync(cur, 0, (size_t)N * sizeof(int), stream);
    count_k<<<(E + 255) / 256, blk, 0, stream>>>(eidx, cur, E);
    scan_part_k<<<P, blk, 0, stream>>>(cur, psum, N);
    scan_mid_k<<<1, 1024, 0, stream>>>(psum, P);
    scan_fin_k<<<P, blk, 0, stream>>>(cur, psum, rs, N);
    scatter_k<<<(E + 255) / 256, blk, 0, stream>>>(eidx, cur, csr, E);

    // 1) Q/K/V = LN1(node) @ {Wq,Wk,Wv} (one fused kernel)
    qkv_k<<<rbN, blk, 0, stream>>>(node, N, (const short*)WqT, (const short*)WkT,
                                   (const short*)WvT, g1n, b1n, Qb, Kb, Vb);

    // 2) EDGE MEGA: LN1(edge)->PE->score->wE->e2->LN2->FFN->e_out
    mega_k<true><<<rbE, blk, 0, stream>>>(
        edgef, edgef, E, eidx, E, Qb, Kb,
        (const short*)WeT, (const short*)WoeT, (const short*)W1eT, (const short*)W2eT,
        g1e, b1e, g2e, b2e, bo_e, wEb, oute);

    // 3) node aggregation via CSR: wVd = segsum(w*V[src]) / (segsum(w)+1e-6)
    agg_k<<<(N + 7) / 8, blk, 0, stream>>>(Vb, wEb, csr, rs, wVd, N);

    // 4) NODE MEGA: h2 = node + wVd@Wo_n + bo_n -> LN2 -> FFN -> h_out
    mega_k<false><<<rbN, blk, 0, stream>>>(
        wVd, node, N, nullptr, 0, nullptr, nullptr,
        nullptr, (const short*)WonT, (const short*)W1nT, (const short*)W2nT,
        nullptr, nullptr, g2n, b2n, bo_n, nullptr, outn);
}